// Round 3
// baseline (375.840 us; speedup 1.0000x reference)
//
#include <hip/hip_runtime.h>
#include <hip/hip_bf16.h>

// ModulatedConv2d: B=16, C_in=C_out=128, H=W=128, K=3, S=512. fp32 I/O.
// Compute: bf16 MFMA (16x16x32), fp32 accumulate.
//
// R7: occupancy-first. Single-h blocks (256 thr / 4 waves), R4's 33.3 KB
// 130-row Xs (restaged per kh, 2 barriers/kh), R6's fragment-order global
// A-loads (no Ws LDS, no per-kw barriers). 33.3 KB LDS + <=128 VGPR ->
// 4 blocks/CU (16 waves/CU) vs R6's 1 block/CU. Latency hiding via TLP.
//  - Bijective XCD-chunk swizzle (grid 2048 % 8 == 0): 2 b's per XCD,
//    wsW working set 576 KB per XCD L2.

#define Bn 16
#define Cc 128
#define HW 128
#define Sv 512

typedef __bf16 bf16x8 __attribute__((ext_vector_type(8)));
typedef float f32x4 __attribute__((ext_vector_type(4)));
typedef unsigned short ushort8 __attribute__((ext_vector_type(8)));

static __device__ __forceinline__ unsigned short bf16bits(float f) {
    return __builtin_bit_cast(unsigned short, __float2bfloat16(f));
}

// ---------------- kernel 1: s[b][ci] = style[b,:] . mod_w[ci,:] + mod_b[ci]
__global__ __launch_bounds__(64) void k_style(const float* __restrict__ style,
                                              const float* __restrict__ mod_w,
                                              const float* __restrict__ mod_b,
                                              float* __restrict__ s_out) {
    int b = blockIdx.x >> 7, ci = blockIdx.x & 127;
    int lane = threadIdx.x;
    const float* st = style + (size_t)b * Sv;
    const float* mw = mod_w + (size_t)ci * Sv;
    float acc = 0.f;
#pragma unroll
    for (int k = 0; k < Sv; k += 64)
        acc += st[k + lane] * mw[k + lane];
#pragma unroll
    for (int off = 32; off > 0; off >>= 1)
        acc += __shfl_down(acc, off, 64);
    if (lane == 0) s_out[b * Cc + ci] = acc + mod_b[ci];
}

// ---------------- kernel 2: modulate + demodulate (fp32), store bf16 in
// MFMA-FRAGMENT order:
//   wsW[((b*9 + j)*32 + frag)*512 + lane*8 + e]
//   frag = (co>>6)*16 + ((co>>4)&3)*4 + (ci>>5)      (m2*16 + mi*4 + ks)
//   lane = ((ci>>3)&3)*16 + (co&15)                  (quad*16 + l15)
//   e    = ci&7
// so that in k_conv, lane l's bf16x8 at (frag, l) holds
//   A[co = m2*64+mi*16+(l&15)][k = (ks*4+(l>>4))*8 .. +7]
// Writes repacked via LDS into 16B chunks (coalescing).
__global__ __launch_bounds__(128) void k_mod(const float* __restrict__ weight,
                                             const float* __restrict__ s,
                                             __hip_bfloat16* __restrict__ wsW) {
    int b = blockIdx.x >> 7;
    int co = blockIdx.x & 127;
    int ci = threadIdx.x;
    float sv = s[b * Cc + ci];
    const float* wp = weight + ((size_t)co * Cc + ci) * 9;
    float wv[9];
    float ss = 0.f;
#pragma unroll
    for (int j = 0; j < 9; j++) {
        wv[j] = wp[j] * sv;
        ss += wv[j] * wv[j];
    }
    __shared__ float red[128];
    __shared__ __align__(16) __bf16 wo[9 * 128];  // j-major
    red[ci] = ss;
    __syncthreads();
    for (int s2 = 64; s2 > 0; s2 >>= 1) {
        if (ci < s2) red[ci] += red[ci + s2];
        __syncthreads();
    }
    float dec = rsqrtf(red[0] + 1e-8f);
#pragma unroll
    for (int j = 0; j < 9; j++)
        wo[j * 128 + ci] = __float2bfloat16(wv[j] * dec);
    __syncthreads();
    // 144 chunks of 16B: chunk c = (j, g), ci = g*8..g*8+7
    int fragbase = ((co >> 6) << 4) | (((co >> 4) & 3) << 2);
#pragma unroll
    for (int it = 0; it < 2; it++) {
        int c = it * 128 + ci;
        if (c < 144) {
            int j = c >> 4, g = c & 15;
            bf16x8 chunk = *(const bf16x8*)(&wo[j * 128 + g * 8]);
            size_t off = (((size_t)b * 9 + j) * 32 + fragbase + (g >> 2)) * 512 +
                         (size_t)(((g & 3) << 4) | (co & 15)) * 8;
            *(bf16x8*)(wsW + off) = chunk;
        }
    }
}

// ---------------- kernel 3: implicit-GEMM conv via MFMA.
// block = (b, h). 4 waves, each computes 64(co) x 64(w) of the 128x128 tile.
// Xs: 130 rows (row r = x-col r-1; rows 0,129 zero), swizzled:
//     elem (row, ci) at  row*128 + (((ci>>3) ^ (row&7))<<3) + (ci&7)
// A: fragment-order global loads (L2-resident), no Ws LDS, no per-kw barriers.
__global__ __launch_bounds__(256, 4) void k_conv(const float* __restrict__ x,
                                                 const __hip_bfloat16* __restrict__ wsW,
                                                 float* __restrict__ out) {
    __shared__ __align__(16) __bf16 Xs[130 * 128];  // 33.3 KB

    int bx0 = blockIdx.x;
    int bx = (bx0 & 7) * 256 + (bx0 >> 3);  // XCD-chunk swizzle, bijective (2048%8==0)
    int b = bx >> 7, h = bx & 127;
    int t = threadIdx.x;
    int lane = t & 63;
    int wvid = t >> 6;
    int wave_m = wvid >> 1, wave_n = wvid & 1;
    int l15 = lane & 15, quad = lane >> 4;

    f32x4 acc[4][4] = {};

    const float* xb = x + (size_t)b * (Cc * HW * HW);
    // A-fragment base for this wave's co-half
    const __hip_bfloat16* wb2 =
        wsW + ((size_t)b * 9) * (32 * 512) + (size_t)(wave_m * 16) * 512 + lane * 8;

    // zero edge rows 0 and 129 (once; staging never touches them)
    if (t < 32) {
        int row = (t < 16) ? 0 : 129;
        int g = t & 15;
        *(bf16x8*)(&Xs[row * 128 + g * 8]) = (bf16x8){};
    }

    for (int kh = 0; kh < 3; kh++) {
        int hp = h + kh - 1;
        if ((unsigned)hp >= (unsigned)HW) continue;  // block-uniform; zero contribution

        __syncthreads();  // prior compute reads of Xs done (also orders edge-zeroing)
        // stage x[b, :, hp, :] -> bf16 swizzled Xs rows 1..128
        // item id: w = id&127 (lanes->consecutive w: coalesced), cig = id>>7
        const float* xr = xb + (size_t)hp * HW;
#pragma unroll
        for (int it = 0; it < 8; it++) {
            int id = it * 256 + t;
            int w = id & 127;
            int cig = id >> 7;
            const float* p = xr + (size_t)cig * 8 * (HW * HW) + w;
            ushort8 pk;
#pragma unroll
            for (int j = 0; j < 8; j++)
                pk[j] = bf16bits(p[(size_t)j * (HW * HW)]);
            int row = w + 1;
            int g2 = cig ^ (row & 7);
            *(bf16x8*)(&Xs[row * 128 + (g2 << 3)]) = __builtin_bit_cast(bf16x8, pk);
        }
        __syncthreads();  // Xs visible

        for (int kw = 0; kw < 3; kw++) {
            const __hip_bfloat16* af = wb2 + (size_t)(kh * 3 + kw) * (32 * 512);
#pragma unroll
            for (int ks = 0; ks < 4; ks++) {
                int kg = ks * 4 + quad;  // k0 = kg*8
                bf16x8 a[4], bfr[4];
#pragma unroll
                for (int mi = 0; mi < 4; mi++)
                    a[mi] = *(const bf16x8*)(af + (size_t)(mi * 4 + ks) * 512);
#pragma unroll
                for (int ni = 0; ni < 4; ni++) {
                    int row = wave_n * 64 + ni * 16 + l15 + kw;  // x-col w+kw-1 -> row w+kw
                    bfr[ni] = *(const bf16x8*)(&Xs[row * 128 + ((kg ^ (row & 7)) << 3)]);
                }
#pragma unroll
                for (int mi = 0; mi < 4; mi++)
#pragma unroll
                    for (int ni = 0; ni < 4; ni++)
                        acc[mi][ni] = __builtin_amdgcn_mfma_f32_16x16x32_bf16(
                            a[mi], bfr[ni], acc[mi][ni], 0, 0, 0);
            }
        }
    }

    // epilogue: co = quad*4+r (+16*mi +64*wave_m), w = l15 (+16*ni +64*wave_n)
    float* ob = out + (size_t)b * (Cc * HW * HW) + h * HW;
#pragma unroll
    for (int mi = 0; mi < 4; mi++) {
#pragma unroll
        for (int ni = 0; ni < 4; ni++) {
            int w = wave_n * 64 + ni * 16 + l15;
#pragma unroll
            for (int r = 0; r < 4; r++) {
                int co = wave_m * 64 + mi * 16 + quad * 4 + r;
                ob[(size_t)co * (HW * HW) + w] = acc[mi][ni][r];
            }
        }
    }
}

extern "C" void kernel_launch(void* const* d_in, const int* in_sizes, int n_in,
                              void* d_out, int out_size, void* d_ws, size_t ws_size,
                              hipStream_t stream) {
    const float* x      = (const float*)d_in[0];
    const float* style  = (const float*)d_in[1];
    const float* weight = (const float*)d_in[2];
    const float* mod_w  = (const float*)d_in[3];
    const float* mod_b  = (const float*)d_in[4];
    float* out = (float*)d_out;

    // workspace: s (fp32, 8KB) | wsW (bf16 fragment-order, 4.72MB)
    float* s_ws = (float*)d_ws;
    __hip_bfloat16* wsW = (__hip_bfloat16*)((char*)d_ws + 8192);

    k_style<<<Bn * Cc, 64, 0, stream>>>(style, mod_w, mod_b, s_ws);
    k_mod<<<Bn * Cc, 128, 0, stream>>>(weight, s_ws, wsW);
    k_conv<<<Bn * HW, 256, 0, stream>>>(x, wsW, out);
}

// Round 4
// 319.888 us; speedup vs baseline: 1.1749x; 1.1749x over previous
//
#include <hip/hip_runtime.h>
#include <hip/hip_bf16.h>

// ModulatedConv2d: B=16, C_in=C_out=128, H=W=128, K=3, S=512. fp32 I/O.
// Compute: bf16 MFMA (16x16x32), fp32 accumulate.
//
// R8: R4's proven geometry (256 thr / 4 waves, 33.3 KB Xs, 2 blocks/CU)
// + barrier-free A-from-global (fragment-order wsW, L2-resident)
// + half-tap ROLLING REGISTER PREFETCH of A (2x8 bf16x8 buffers, 64 VGPR):
//   group g+1's 8 loads issue before group g's 32 MFMAs -> L2 latency hidden.
// __launch_bounds__(256,2): 256-reg cap (est ~170 used), 8 waves/CU.
// OOB kh rows staged as zeros (exact) so the 18-group pipeline is static.

#define Bn 16
#define Cc 128
#define HW 128
#define Sv 512

typedef __bf16 bf16x8 __attribute__((ext_vector_type(8)));
typedef float f32x4 __attribute__((ext_vector_type(4)));
typedef unsigned short ushort8 __attribute__((ext_vector_type(8)));

static __device__ __forceinline__ unsigned short bf16bits(float f) {
    return __builtin_bit_cast(unsigned short, __float2bfloat16(f));
}

// ---------------- kernel 1: s[b][ci] = style[b,:] . mod_w[ci,:] + mod_b[ci]
__global__ __launch_bounds__(64) void k_style(const float* __restrict__ style,
                                              const float* __restrict__ mod_w,
                                              const float* __restrict__ mod_b,
                                              float* __restrict__ s_out) {
    int b = blockIdx.x >> 7, ci = blockIdx.x & 127;
    int lane = threadIdx.x;
    const float* st = style + (size_t)b * Sv;
    const float* mw = mod_w + (size_t)ci * Sv;
    float acc = 0.f;
#pragma unroll
    for (int k = 0; k < Sv; k += 64)
        acc += st[k + lane] * mw[k + lane];
#pragma unroll
    for (int off = 32; off > 0; off >>= 1)
        acc += __shfl_down(acc, off, 64);
    if (lane == 0) s_out[b * Cc + ci] = acc + mod_b[ci];
}

// ---------------- kernel 2: modulate + demodulate (fp32), store bf16 in
// MFMA-FRAGMENT order:
//   wsW[((b*9 + j)*32 + frag)*512 + lane*8 + e]
//   frag = (co>>6)*16 + ((co>>4)&3)*4 + (ci>>5)      (m2*16 + mi*4 + ks)
//   lane = ((ci>>3)&3)*16 + (co&15)                  (quad*16 + l15)
//   e    = ci&7
// Writes repacked via LDS into 16B chunks (coalescing).
__global__ __launch_bounds__(128) void k_mod(const float* __restrict__ weight,
                                             const float* __restrict__ s,
                                             __hip_bfloat16* __restrict__ wsW) {
    int b = blockIdx.x >> 7;
    int co = blockIdx.x & 127;
    int ci = threadIdx.x;
    float sv = s[b * Cc + ci];
    const float* wp = weight + ((size_t)co * Cc + ci) * 9;
    float wv[9];
    float ss = 0.f;
#pragma unroll
    for (int j = 0; j < 9; j++) {
        wv[j] = wp[j] * sv;
        ss += wv[j] * wv[j];
    }
    __shared__ float red[128];
    __shared__ __align__(16) __bf16 wo[9 * 128];  // j-major
    red[ci] = ss;
    __syncthreads();
    for (int s2 = 64; s2 > 0; s2 >>= 1) {
        if (ci < s2) red[ci] += red[ci + s2];
        __syncthreads();
    }
    float dec = rsqrtf(red[0] + 1e-8f);
#pragma unroll
    for (int j = 0; j < 9; j++)
        wo[j * 128 + ci] = __float2bfloat16(wv[j] * dec);
    __syncthreads();
    // 144 chunks of 16B: chunk c = (j, g), ci = g*8..g*8+7
    int fragbase = ((co >> 6) << 4) | (((co >> 4) & 3) << 2);
#pragma unroll
    for (int it = 0; it < 2; it++) {
        int c = it * 128 + ci;
        if (c < 144) {
            int j = c >> 4, g = c & 15;
            bf16x8 chunk = *(const bf16x8*)(&wo[j * 128 + g * 8]);
            size_t off = (((size_t)b * 9 + j) * 32 + fragbase + (g >> 2)) * 512 +
                         (size_t)(((g & 3) << 4) | (co & 15)) * 8;
            *(bf16x8*)(wsW + off) = chunk;
        }
    }
}

// ---------------- kernel 3: implicit-GEMM conv via MFMA.
// block = (b, h). 4 waves, each 64(co) x 64(w) of the 128x128 tile.
// Xs: 130 rows (row r = x-col r-1; rows 0,129 zero), XOR-swizzled.
// A: fragment-order global loads, rolling half-tap register double-buffer.
__global__ __launch_bounds__(256, 2) void k_conv(const float* __restrict__ x,
                                                 const __hip_bfloat16* __restrict__ wsW,
                                                 float* __restrict__ out) {
    __shared__ __align__(16) __bf16 Xs[130 * 128];  // 33.3 KB

    int bx0 = blockIdx.x;
    int bx = (bx0 & 7) * 256 + (bx0 >> 3);  // XCD-chunk swizzle, bijective (2048%8==0)
    int b = bx >> 7, h = bx & 127;
    int t = threadIdx.x;
    int lane = t & 63;
    int wvid = t >> 6;
    int wave_m = wvid >> 1, wave_n = wvid & 1;
    int l15 = lane & 15, quad = lane >> 4;

    f32x4 acc[4][4] = {};
    bf16x8 pe[8], po[8];  // even/odd half-tap A buffers (g parity)

    const float* xb = x + (size_t)b * (Cc * HW * HW);
    // A-fragment base for this wave's co-half; frag f at wb2 + f*512 elems
    const __hip_bfloat16* wb2 =
        wsW + ((size_t)b * 9) * (32 * 512) + (size_t)(wave_m * 16) * 512 + lane * 8;

    // prologue: prefetch group 0 (tap 0, ks 0..1) into pe
#pragma unroll
    for (int mi = 0; mi < 4; mi++)
#pragma unroll
        for (int j = 0; j < 2; j++)
            pe[mi * 2 + j] = *(const bf16x8*)(wb2 + (size_t)(mi * 4 + j) * 512);

    // zero edge rows 0 and 129 (once; staging never touches them)
    if (t < 32) {
        int row = (t < 16) ? 0 : 129;
        int g = t & 15;
        *(bf16x8*)(&Xs[row * 128 + g * 8]) = (bf16x8){};
    }

#pragma unroll
    for (int kh = 0; kh < 3; kh++) {
        int hp = h + kh - 1;
        bool ok = (unsigned)hp < (unsigned)HW;  // block-uniform; OOB -> stage zeros
        __syncthreads();  // prior compute reads of Xs done
        const float* xr = xb + (size_t)hp * HW;
#pragma unroll
        for (int it = 0; it < 8; it++) {
            int id = it * 256 + t;
            int w = id & 127;
            int cig = id >> 7;
            ushort8 pk = {};
            if (ok) {
                const float* p = xr + (size_t)cig * 8 * (HW * HW) + w;
#pragma unroll
                for (int j = 0; j < 8; j++)
                    pk[j] = bf16bits(p[(size_t)j * (HW * HW)]);
            }
            int row = w + 1;
            int g2 = cig ^ (row & 7);
            *(bf16x8*)(&Xs[row * 128 + (g2 << 3)]) = __builtin_bit_cast(bf16x8, pk);
        }
        __syncthreads();  // Xs visible

#pragma unroll
        for (int kw = 0; kw < 3; kw++) {
#pragma unroll
            for (int half = 0; half < 2; half++) {
                const int g = (kh * 3 + kw) * 2 + half;  // 0..17, compile-time
                // ---- prefetch group g+1 into the other parity buffer ----
                if (g < 17) {
                    const int tp1 = (g + 1) >> 1;
                    const int kslo1 = ((g + 1) & 1) * 2;
                    const __hip_bfloat16* af = wb2 + (size_t)tp1 * (32 * 512);
                    if ((g & 1) == 0) {
#pragma unroll
                        for (int mi = 0; mi < 4; mi++)
#pragma unroll
                            for (int j = 0; j < 2; j++)
                                po[mi * 2 + j] = *(const bf16x8*)(
                                    af + (size_t)(mi * 4 + kslo1 + j) * 512);
                    } else {
#pragma unroll
                        for (int mi = 0; mi < 4; mi++)
#pragma unroll
                            for (int j = 0; j < 2; j++)
                                pe[mi * 2 + j] = *(const bf16x8*)(
                                    af + (size_t)(mi * 4 + kslo1 + j) * 512);
                    }
                }
                // ---- compute group g from current parity buffer ----
#pragma unroll
                for (int j = 0; j < 2; j++) {
                    const int ks = half * 2 + j;
                    int kg = ks * 4 + quad;  // k0 = kg*8
                    bf16x8 bfr[4];
#pragma unroll
                    for (int ni = 0; ni < 4; ni++) {
                        int row = wave_n * 64 + ni * 16 + l15 + kw;  // x-col w+kw-1
                        bfr[ni] = *(const bf16x8*)(
                            &Xs[row * 128 + ((kg ^ (row & 7)) << 3)]);
                    }
                    if ((g & 1) == 0) {
#pragma unroll
                        for (int mi = 0; mi < 4; mi++)
#pragma unroll
                            for (int ni = 0; ni < 4; ni++)
                                acc[mi][ni] = __builtin_amdgcn_mfma_f32_16x16x32_bf16(
                                    pe[mi * 2 + j], bfr[ni], acc[mi][ni], 0, 0, 0);
                    } else {
#pragma unroll
                        for (int mi = 0; mi < 4; mi++)
#pragma unroll
                            for (int ni = 0; ni < 4; ni++)
                                acc[mi][ni] = __builtin_amdgcn_mfma_f32_16x16x32_bf16(
                                    po[mi * 2 + j], bfr[ni], acc[mi][ni], 0, 0, 0);
                    }
                }
            }
        }
    }

    // epilogue: co = quad*4+r (+16*mi +64*wave_m), w = l15 (+16*ni +64*wave_n)
    float* ob = out + (size_t)b * (Cc * HW * HW) + h * HW;
#pragma unroll
    for (int mi = 0; mi < 4; mi++) {
#pragma unroll
        for (int ni = 0; ni < 4; ni++) {
            int w = wave_n * 64 + ni * 16 + l15;
#pragma unroll
            for (int r = 0; r < 4; r++) {
                int co = wave_m * 64 + mi * 16 + quad * 4 + r;
                ob[(size_t)co * (HW * HW) + w] = acc[mi][ni][r];
            }
        }
    }
}

extern "C" void kernel_launch(void* const* d_in, const int* in_sizes, int n_in,
                              void* d_out, int out_size, void* d_ws, size_t ws_size,
                              hipStream_t stream) {
    const float* x      = (const float*)d_in[0];
    const float* style  = (const float*)d_in[1];
    const float* weight = (const float*)d_in[2];
    const float* mod_w  = (const float*)d_in[3];
    const float* mod_b  = (const float*)d_in[4];
    float* out = (float*)d_out;

    // workspace: s (fp32, 8KB) | wsW (bf16 fragment-order, 4.72MB)
    float* s_ws = (float*)d_ws;
    __hip_bfloat16* wsW = (__hip_bfloat16*)((char*)d_ws + 8192);

    k_style<<<Bn * Cc, 64, 0, stream>>>(style, mod_w, mod_b, s_ws);
    k_mod<<<Bn * Cc, 128, 0, stream>>>(weight, s_ws, wsW);
    k_conv<<<Bn * HW, 256, 0, stream>>>(x, wsW, out);
}